// Round 8
// baseline (186.819 us; speedup 1.0000x reference)
//
#include <hip/hip_runtime.h>
#include <hip/hip_bf16.h>

// Problem constants
#define BB 64
#define II 1152
#define OO 32
#define DD 8
#define HH 16
#define BOH (BB * OO * HH)    // 32768
#define WTILE (OO * DD * HH)  // 4096 floats per i

// Pass-0 (fp32) decomposition
#define IC0  9
#define NIC0 128
// Pass-1/2 (bf16-W) decomposition: 3 steps of 2 i-tiles
#define IC2  6
#define NIC2 192
#define NBB  16    // b per block
#define NBG  4     // b-groups
#define NJB  4     // b per thread
#define WS   132   // fp32 padded LDS row stride (dword stride mod 32 == 4, measured clean)
#define WSB  136   // bf16 padded row stride in ushorts (same dword-bank geometry)
#define TBF  4352  // bf16 LDS tile: OO * WSB ushorts (8.5 KB)

// ---------------------------------------------------------------------------
// bf16 helpers: RNE pack (fp32 pair -> dword) and unpack (dword -> 2 fp32)
// ---------------------------------------------------------------------------
__device__ __forceinline__ unsigned bfpack(float a, float b)
{
    unsigned ua = __float_as_uint(a); ua += 0x7FFFu + ((ua >> 16) & 1u);
    unsigned ub = __float_as_uint(b); ub += 0x7FFFu + ((ub >> 16) & 1u);
    return (ua >> 16) | (ub & 0xFFFF0000u);
}
__device__ __forceinline__ float bflo(unsigned x) { return __uint_as_float(x << 16); }
__device__ __forceinline__ float bfhi(unsigned x) { return __uint_as_float(x & 0xFFFF0000u); }

// DPP rotate-reduce over 16-lane rows (VALU pipe), + swizzle for 32-lane o-sum
__device__ __forceinline__ float row_sum16(float x)
{
    x += __int_as_float(__builtin_amdgcn_update_dpp(0, __float_as_int(x), 0x121, 0xF, 0xF, false));
    x += __int_as_float(__builtin_amdgcn_update_dpp(0, __float_as_int(x), 0x122, 0xF, 0xF, false));
    x += __int_as_float(__builtin_amdgcn_update_dpp(0, __float_as_int(x), 0x124, 0xF, 0xF, false));
    x += __int_as_float(__builtin_amdgcn_update_dpp(0, __float_as_int(x), 0x128, 0xF, 0xF, false));
    return x;
}
__device__ __forceinline__ float o_sum32(float x)
{
    float s = row_sum16(x);
    s += __int_as_float(__builtin_amdgcn_ds_swizzle(__float_as_int(s), 0x401F));
    return s;
}

// ---------------------------------------------------------------------------
// Pass 0 (fp32 W): R7-proven structure + free W->bf16 conversion: blocks with
// blockIdx.y==0 RNE-convert each staged tile and store it to wb (each i once).
// Grid (NIC0, NBG) x 256. tid = o + 32*hh + 64*bq.
// ---------------------------------------------------------------------------
template<int PASS, bool ATOMIC>
__global__ __launch_bounds__(256)
void pass_kernel(const float* __restrict__ u, const float* __restrict__ w,
                 const float* __restrict__ pv0, const float* __restrict__ pv1,
                 float* __restrict__ out, unsigned* __restrict__ wb)
{
    __shared__ float Wsh[2][OO * WS];     // 2 x 16.5 KB double buffer

    const int tid   = threadIdx.x;
    const int o     = tid & 31;
    const int hh    = (tid >> 5) & 1;
    const int bq    = tid >> 6;
    const int bbase = blockIdx.y * NBB;
    const int i0    = blockIdx.x * IC0;
    const int hofs  = hh * 8;
    const bool cvt  = (wb != nullptr) && (blockIdx.y == 0);

    float vsum[NJB][8];
    if (PASS >= 1) {
        #pragma unroll
        for (int jb = 0; jb < NJB; jb++) {
            const int b = bbase + bq * NJB + jb;
            const float* p = pv0 + ((b * OO + o) * HH + hofs);
            float4 a = *(const float4*)p;
            float4 c = *(const float4*)(p + 4);
            vsum[jb][0] = a.x; vsum[jb][1] = a.y; vsum[jb][2] = a.z; vsum[jb][3] = a.w;
            vsum[jb][4] = c.x; vsum[jb][5] = c.y; vsum[jb][6] = c.z; vsum[jb][7] = c.w;
            if (PASS == 2) {
                const float* q = pv1 + ((b * OO + o) * HH + hofs);
                float4 a2 = *(const float4*)q;
                float4 c2 = *(const float4*)(q + 4);
                vsum[jb][0] += a2.x; vsum[jb][1] += a2.y; vsum[jb][2] += a2.z; vsum[jb][3] += a2.w;
                vsum[jb][4] += c2.x; vsum[jb][5] += c2.y; vsum[jb][6] += c2.z; vsum[jb][7] += c2.w;
            }
        }
    }

    float sacc[NJB][8];
    #pragma unroll
    for (int jb = 0; jb < NJB; jb++)
        #pragma unroll
        for (int h2 = 0; h2 < 8; h2++) sacc[jb][h2] = 0.f;

    // Prologue: stage W[i0] into buffer 0 (+ optional bf16 store)
    {
        const float* wg = w + (size_t)i0 * WTILE;
        #pragma unroll
        for (int j = 0; j < 4; j++) {
            const int c = tid + j * 256;
            float4 v4 = *(const float4*)(wg + c * 4);
            *(float4*)&Wsh[0][(c >> 5) * WS + (c & 31) * 4] = v4;
            if (cvt) {
                uint2 p2 = make_uint2(bfpack(v4.x, v4.y), bfpack(v4.z, v4.w));
                *(uint2*)(wb + (size_t)i0 * 2048 + c * 2) = p2;
            }
        }
    }
    __syncthreads();

    for (int ii = 0; ii < IC0; ii++) {
        const float* wcur = Wsh[ii & 1];
        const bool pf = (ii + 1 < IC0);
        float4 t0, t1, t2, t3;
        if (pf) {
            const float* wg = w + (size_t)(i0 + ii + 1) * WTILE;
            t0 = *(const float4*)(wg + (tid      ) * 4);
            t1 = *(const float4*)(wg + (tid + 256) * 4);
            t2 = *(const float4*)(wg + (tid + 512) * 4);
            t3 = *(const float4*)(wg + (tid + 768) * 4);
        }

        // u via broadcast global loads (wave-uniform address)
        float us[NJB][8];
        #pragma unroll
        for (int jb = 0; jb < NJB; jb++) {
            const float* ub = u + ((size_t)(bbase + bq * NJB + jb) * II + (i0 + ii)) * DD;
            float4 a = *(const float4*)ub;
            float4 c = *(const float4*)(ub + 4);
            us[jb][0] = a.x; us[jb][1] = a.y; us[jb][2] = a.z; us[jb][3] = a.w;
            us[jb][4] = c.x; us[jb][5] = c.y; us[jb][6] = c.z; us[jb][7] = c.w;
        }

        float uh[NJB][8];
        #pragma unroll
        for (int jb = 0; jb < NJB; jb++)
            #pragma unroll
            for (int h2 = 0; h2 < 8; h2++) uh[jb][h2] = 0.f;
        #pragma unroll
        for (int d = 0; d < DD; d++) {
            const float* wp = &wcur[o * WS + d * HH + hofs];
            float4 wa = *(const float4*)wp;
            float4 wc = *(const float4*)(wp + 4);
            const float wv[8] = {wa.x, wa.y, wa.z, wa.w, wc.x, wc.y, wc.z, wc.w};
            #pragma unroll
            for (int jb = 0; jb < NJB; jb++)
                #pragma unroll
                for (int h2 = 0; h2 < 8; h2++)
                    uh[jb][h2] = fmaf(us[jb][d], wv[h2], uh[jb][h2]);
        }

        float cc[NJB];
        if (PASS == 0) {
            #pragma unroll
            for (int jb = 0; jb < NJB; jb++) cc[jb] = 1.0f / 32.0f;
        } else {
            #pragma unroll
            for (int jb = 0; jb < NJB; jb++) {
                float lg = 0.f;
                #pragma unroll
                for (int h2 = 0; h2 < 8; h2++)
                    lg = fmaf(vsum[jb][h2], uh[jb][h2], lg);
                lg += __shfl_xor(lg, 32, 64);
                const float e = __expf(lg);
                const float se = o_sum32(e);
                cc[jb] = __fdividef(e, se);
            }
        }

        #pragma unroll
        for (int jb = 0; jb < NJB; jb++)
            #pragma unroll
            for (int h2 = 0; h2 < 8; h2++)
                sacc[jb][h2] = fmaf(cc[jb], uh[jb][h2], sacc[jb][h2]);

        if (pf) {
            float* wn = Wsh[(ii + 1) & 1];
            const int c0 = tid, c1 = tid + 256, c2 = tid + 512, c3 = tid + 768;
            *(float4*)&wn[(c0 >> 5) * WS + (c0 & 31) * 4] = t0;
            *(float4*)&wn[(c1 >> 5) * WS + (c1 & 31) * 4] = t1;
            *(float4*)&wn[(c2 >> 5) * WS + (c2 & 31) * 4] = t2;
            *(float4*)&wn[(c3 >> 5) * WS + (c3 & 31) * 4] = t3;
            if (cvt) {
                unsigned* wt = wb + (size_t)(i0 + ii + 1) * 2048;
                *(uint2*)(wt + c0 * 2) = make_uint2(bfpack(t0.x, t0.y), bfpack(t0.z, t0.w));
                *(uint2*)(wt + c1 * 2) = make_uint2(bfpack(t1.x, t1.y), bfpack(t1.z, t1.w));
                *(uint2*)(wt + c2 * 2) = make_uint2(bfpack(t2.x, t2.y), bfpack(t2.z, t2.w));
                *(uint2*)(wt + c3 * 2) = make_uint2(bfpack(t3.x, t3.y), bfpack(t3.z, t3.w));
            }
        }
        __syncthreads();
    }

    #pragma unroll
    for (int jb = 0; jb < NJB; jb++) {
        const int b = bbase + bq * NJB + jb;
        if (ATOMIC) {
            float* p = out + ((b * OO + o) * HH + hofs);
            #pragma unroll
            for (int h2 = 0; h2 < 8; h2++) atomicAdd(p + h2, sacc[jb][h2]);
        } else {
            float* p = out + ((size_t)blockIdx.x * BB + b) * (OO * HH) + o * HH + hofs;
            *(float4*)p       = make_float4(sacc[jb][0], sacc[jb][1], sacc[jb][2], sacc[jb][3]);
            *(float4*)(p + 4) = make_float4(sacc[jb][4], sacc[jb][5], sacc[jb][6], sacc[jb][7]);
        }
    }
}

// ---------------------------------------------------------------------------
// Passes 1/2 (bf16 W from ws): grid (NIC2, NBG) = 768 blocks x 256 = 3/CU.
// Each LDS buffer holds TWO 8.5 KB i-tiles -> one barrier per 2 i (4/pass vs 10).
// DS reads halve (8 b128/thread/i); W global traffic halves. u/v/softmax fp32.
// ---------------------------------------------------------------------------
template<int PASS>
__global__ __launch_bounds__(256)
void pass_bf(const float* __restrict__ u, const unsigned* __restrict__ wb,
             const float* __restrict__ pv0, const float* __restrict__ pv1,
             float* __restrict__ out)
{
    __shared__ unsigned short Wb[2][2 * TBF];   // 2 buffers x 2 tiles = 34 KB

    const int tid   = threadIdx.x;
    const int o     = tid & 31;
    const int hh    = (tid >> 5) & 1;
    const int bq    = tid >> 6;
    const int bbase = blockIdx.y * NBB;
    const int i0    = blockIdx.x * IC2;
    const int hofs  = hh * 8;

    float vsum[NJB][8];
    #pragma unroll
    for (int jb = 0; jb < NJB; jb++) {
        const int b = bbase + bq * NJB + jb;
        const float* p = pv0 + ((b * OO + o) * HH + hofs);
        float4 a = *(const float4*)p;
        float4 c = *(const float4*)(p + 4);
        vsum[jb][0] = a.x; vsum[jb][1] = a.y; vsum[jb][2] = a.z; vsum[jb][3] = a.w;
        vsum[jb][4] = c.x; vsum[jb][5] = c.y; vsum[jb][6] = c.z; vsum[jb][7] = c.w;
        if (PASS == 2) {
            const float* q = pv1 + ((b * OO + o) * HH + hofs);
            float4 a2 = *(const float4*)q;
            float4 c2 = *(const float4*)(q + 4);
            vsum[jb][0] += a2.x; vsum[jb][1] += a2.y; vsum[jb][2] += a2.z; vsum[jb][3] += a2.w;
            vsum[jb][4] += c2.x; vsum[jb][5] += c2.y; vsum[jb][6] += c2.z; vsum[jb][7] += c2.w;
        }
    }

    float sacc[NJB][8];
    #pragma unroll
    for (int jb = 0; jb < NJB; jb++)
        #pragma unroll
        for (int h2 = 0; h2 < 8; h2++) sacc[jb][h2] = 0.f;

    // Prologue: stage step 0 (tiles i0, i0+1): 1024 bf16-chunks of 16 B, 4/thread.
    {
        const uint4* wg = (const uint4*)(wb + (size_t)i0 * 2048);
        #pragma unroll
        for (int j = 0; j < 4; j++) {
            const int c  = tid + j * 256;
            uint4 v4 = wg[c];
            const int cc = c & 511;
            *(uint4*)&Wb[0][(c >> 9) * TBF + (cc >> 4) * WSB + (cc & 15) * 8] = v4;
        }
    }
    __syncthreads();

    for (int s = 0; s < IC2 / 2; s++) {
        const unsigned short* wbuf = Wb[s & 1];
        const bool pf = (s + 1 < IC2 / 2);
        uint4 t0, t1, t2, t3;
        if (pf) {
            const uint4* wg = (const uint4*)(wb + (size_t)(i0 + 2 * s + 2) * 2048);
            t0 = wg[tid];
            t1 = wg[tid + 256];
            t2 = wg[tid + 512];
            t3 = wg[tid + 768];
        }

        #pragma unroll
        for (int it = 0; it < 2; it++) {
            const int i = i0 + 2 * s + it;
            const unsigned short* wt = &wbuf[it * TBF + o * WSB + hofs];

            float us[NJB][8];
            #pragma unroll
            for (int jb = 0; jb < NJB; jb++) {
                const float* ub = u + ((size_t)(bbase + bq * NJB + jb) * II + i) * DD;
                float4 a = *(const float4*)ub;
                float4 c = *(const float4*)(ub + 4);
                us[jb][0] = a.x; us[jb][1] = a.y; us[jb][2] = a.z; us[jb][3] = a.w;
                us[jb][4] = c.x; us[jb][5] = c.y; us[jb][6] = c.z; us[jb][7] = c.w;
            }

            float uh[NJB][8];
            #pragma unroll
            for (int jb = 0; jb < NJB; jb++)
                #pragma unroll
                for (int h2 = 0; h2 < 8; h2++) uh[jb][h2] = 0.f;
            #pragma unroll
            for (int d = 0; d < DD; d++) {
                const uint4 wd = *(const uint4*)&wt[d * HH];
                const float wv[8] = { bflo(wd.x), bfhi(wd.x), bflo(wd.y), bfhi(wd.y),
                                      bflo(wd.z), bfhi(wd.z), bflo(wd.w), bfhi(wd.w) };
                #pragma unroll
                for (int jb = 0; jb < NJB; jb++)
                    #pragma unroll
                    for (int h2 = 0; h2 < 8; h2++)
                        uh[jb][h2] = fmaf(us[jb][d], wv[h2], uh[jb][h2]);
            }

            float cc[NJB];
            #pragma unroll
            for (int jb = 0; jb < NJB; jb++) {
                float lg = 0.f;
                #pragma unroll
                for (int h2 = 0; h2 < 8; h2++)
                    lg = fmaf(vsum[jb][h2], uh[jb][h2], lg);
                lg += __shfl_xor(lg, 32, 64);
                const float e = __expf(lg);
                const float se = o_sum32(e);
                cc[jb] = __fdividef(e, se);
            }

            #pragma unroll
            for (int jb = 0; jb < NJB; jb++)
                #pragma unroll
                for (int h2 = 0; h2 < 8; h2++)
                    sacc[jb][h2] = fmaf(cc[jb], uh[jb][h2], sacc[jb][h2]);
        }

        if (pf) {
            unsigned short* wn = Wb[(s + 1) & 1];
            #pragma unroll
            for (int j = 0; j < 4; j++) {
                const int c  = tid + j * 256;
                const int cc = c & 511;
                uint4 v4 = (j == 0) ? t0 : (j == 1) ? t1 : (j == 2) ? t2 : t3;
                *(uint4*)&wn[(c >> 9) * TBF + (cc >> 4) * WSB + (cc & 15) * 8] = v4;
            }
            __syncthreads();
        }
    }

    #pragma unroll
    for (int jb = 0; jb < NJB; jb++) {
        const int b = bbase + bq * NJB + jb;
        float* p = out + ((size_t)blockIdx.x * BB + b) * (OO * HH) + o * HH + hofs;
        *(float4*)p       = make_float4(sacc[jb][0], sacc[jb][1], sacc[jb][2], sacc[jb][3]);
        *(float4*)(p + 4) = make_float4(sacc[jb][4], sacc[jb][5], sacc[jb][6], sacc[jb][7]);
    }
}

// Fused reduce-over-chunks + squash (NCH = chunk count of the producing pass).
template<int NCH>
__global__ __launch_bounds__(256)
void reduce_squash_kernel(const float* __restrict__ part, float* __restrict__ v)
{
    const int t = blockIdx.x * blockDim.x + threadIdx.x;
    float acc = 0.f;
    #pragma unroll 16
    for (int ic = 0; ic < NCH; ic++)
        acc += part[(size_t)ic * BOH + t];
    const float sq = row_sum16(acc * acc);
    const float scale = (sq / (1.f + sq)) * rsqrtf(sq + 1e-8f);
    v[t] = acc * scale;
}

// Standalone squash for the atomic tiny-ws fallback.
__global__ __launch_bounds__(256)
void squash_kernel(const float* __restrict__ s, float* __restrict__ v)
{
    const int t = blockIdx.x * blockDim.x + threadIdx.x;
    if (t >= BB * OO) return;
    const float4* sp = (const float4*)(s + t * HH);
    float4 a = sp[0], b = sp[1], c = sp[2], d = sp[3];
    float sq = a.x*a.x + a.y*a.y + a.z*a.z + a.w*a.w
             + b.x*b.x + b.y*b.y + b.z*b.z + b.w*b.w
             + c.x*c.x + c.y*c.y + c.z*c.z + c.w*c.w
             + d.x*d.x + d.y*d.y + d.z*d.z + d.w*d.w;
    const float scale = (sq / (1.f + sq)) * rsqrtf(sq + 1e-8f);
    a.x *= scale; a.y *= scale; a.z *= scale; a.w *= scale;
    b.x *= scale; b.y *= scale; b.z *= scale; b.w *= scale;
    c.x *= scale; c.y *= scale; c.z *= scale; c.w *= scale;
    d.x *= scale; d.y *= scale; d.z *= scale; d.w *= scale;
    float4* vp = (float4*)(v + t * HH);
    vp[0] = a; vp[1] = b; vp[2] = c; vp[3] = d;
}

extern "C" void kernel_launch(void* const* d_in, const int* in_sizes, int n_in,
                              void* d_out, int out_size, void* d_ws, size_t ws_size,
                              hipStream_t stream)
{
    (void)in_sizes; (void)n_in; (void)out_size;
    const float* u = (const float*)d_in[0];
    const float* w = (const float*)d_in[1];
    float* out = (float*)d_out;

    // ws layout: wb (bf16 W, 9.4 MB) | part (NIC2 x BOH) | v0 | v1
    const size_t wb_dwords = (size_t)II * 2048;                     // 2.36M dwords
    const size_t need = wb_dwords * 4 + ((size_t)NIC2 * BOH + 2 * BOH) * 4;  // ~35 MB

    if (ws_size >= need) {
        unsigned* wbp = (unsigned*)d_ws;
        float* part = (float*)d_ws + wb_dwords;
        float* v0   = part + (size_t)NIC2 * BOH;
        float* v1   = v0 + BOH;
        const int rblocks = BOH / 256;                              // 128

        pass_kernel<0, false><<<dim3(NIC0, NBG), 256, 0, stream>>>(u, w, nullptr, nullptr, part, wbp);
        reduce_squash_kernel<NIC0><<<rblocks, 256, 0, stream>>>(part, v0);
        pass_bf<1><<<dim3(NIC2, NBG), 256, 0, stream>>>(u, wbp, v0, nullptr, part);
        reduce_squash_kernel<NIC2><<<rblocks, 256, 0, stream>>>(part, v1);
        pass_bf<2><<<dim3(NIC2, NBG), 256, 0, stream>>>(u, wbp, v0, v1, part);
        reduce_squash_kernel<NIC2><<<rblocks, 256, 0, stream>>>(part, out);
    } else {
        // Tiny-ws fallback: fp32 atomic path.
        float* s0 = (float*)d_ws;
        float* s1 = s0 + BOH;
        float* v0 = s1 + BOH;
        float* v1 = v0 + BOH;
        hipMemsetAsync(d_ws, 0, 2 * BOH * sizeof(float), stream);
        hipMemsetAsync(d_out, 0, BOH * sizeof(float), stream);
        const int sq_blocks = (BB * OO + 255) / 256;

        pass_kernel<0, true><<<dim3(NIC0, NBG), 256, 0, stream>>>(u, w, nullptr, nullptr, s0, nullptr);
        squash_kernel<<<sq_blocks, 256, 0, stream>>>(s0, v0);
        pass_kernel<1, true><<<dim3(NIC0, NBG), 256, 0, stream>>>(u, w, v0, nullptr, s1, nullptr);
        squash_kernel<<<sq_blocks, 256, 0, stream>>>(s1, v1);
        pass_kernel<2, true><<<dim3(NIC0, NBG), 256, 0, stream>>>(u, w, v0, v1, out, nullptr);
        squash_kernel<<<sq_blocks, 256, 0, stream>>>(out, out);
    }
}

// Round 9
// 145.610 us; speedup vs baseline: 1.2830x; 1.2830x over previous
//
#include <hip/hip_runtime.h>
#include <hip/hip_bf16.h>

// Problem constants
#define BB 64
#define II 1152
#define OO 32
#define DD 8
#define HH 16
#define BOH (BB * OO * HH)    // 32768
#define WTILE (OO * DD * HH)  // 4096 floats per i

// Decomposition (R5/R7-proven): NIC * IC == II
#define IC   9
#define NIC  128
#define NBB  16    // b per block
#define NBG  4     // b-groups (NBG * NBB == BB)
#define NJB  4     // b per thread
#define WS   132   // padded LDS row stride (breaks 32-way b128 conflicts)

typedef float v2f __attribute__((ext_vector_type(2)));   // maps to v_pk_*_f32

// ---------------------------------------------------------------------------
// DPP rotate-reduce over 16-lane rows (VALU pipe); + swizzle for 32-lane o-sum
// ---------------------------------------------------------------------------
__device__ __forceinline__ float row_sum16(float x)
{
    x += __int_as_float(__builtin_amdgcn_update_dpp(0, __float_as_int(x), 0x121, 0xF, 0xF, false));
    x += __int_as_float(__builtin_amdgcn_update_dpp(0, __float_as_int(x), 0x122, 0xF, 0xF, false));
    x += __int_as_float(__builtin_amdgcn_update_dpp(0, __float_as_int(x), 0x124, 0xF, 0xF, false));
    x += __int_as_float(__builtin_amdgcn_update_dpp(0, __float_as_int(x), 0x128, 0xF, 0xF, false));
    return x;
}
__device__ __forceinline__ float o_sum32(float x)
{
    float s = row_sum16(x);
    s += __int_as_float(__builtin_amdgcn_ds_swizzle(__float_as_int(s), 0x401F));
    return s;
}

// ---------------------------------------------------------------------------
// Pass kernel (R7 structure + packed fp32 math): one routing iteration.
// Grid (NIC, NBG) = 512 blocks x 256 thr. tid = o + 32*hh + 64*bq.
// Logits are linear in v -> register vsum replaces any logits array.
// W: 2-buffer LDS pipeline (prefetch W[i+1] during compute on W[i]).
// u: broadcast global loads (wave-uniform address, L1 broadcast).
// softmax o-reduction: DPP row_ror + 1 swizzle (VALU pipe, minimal DS).
// Inner math on float2 -> v_pk_fma_f32 (VOP3P: 2 FMA/lane/issue) halves the
// dominant per-i instruction stream (uh 256->128, sacc 32->16, lg 32->16).
// ---------------------------------------------------------------------------
template<int PASS, bool ATOMIC>
__global__ __launch_bounds__(256)
void pass_kernel(const float* __restrict__ u, const float* __restrict__ w,
                 const float* __restrict__ pv0, const float* __restrict__ pv1,
                 float* __restrict__ out)
{
    __shared__ float Wsh[2][OO * WS];     // 2 x 16.5 KB double buffer

    const int tid   = threadIdx.x;
    const int o     = tid & 31;
    const int hh    = (tid >> 5) & 1;
    const int bq    = tid >> 6;           // 0..3
    const int bbase = blockIdx.y * NBB;
    const int i0    = blockIdx.x * IC;
    const int hofs  = hh * 8;

    // vsum = sum of previous v's (constant over i), packed as 4 x float2
    v2f vsum[NJB][4];
    if (PASS >= 1) {
        #pragma unroll
        for (int jb = 0; jb < NJB; jb++) {
            const int b = bbase + bq * NJB + jb;
            const float* p = pv0 + ((b * OO + o) * HH + hofs);
            float4 a = *(const float4*)p;
            float4 c = *(const float4*)(p + 4);
            vsum[jb][0] = (v2f){a.x, a.y}; vsum[jb][1] = (v2f){a.z, a.w};
            vsum[jb][2] = (v2f){c.x, c.y}; vsum[jb][3] = (v2f){c.z, c.w};
            if (PASS == 2) {
                const float* q = pv1 + ((b * OO + o) * HH + hofs);
                float4 a2 = *(const float4*)q;
                float4 c2 = *(const float4*)(q + 4);
                vsum[jb][0] += (v2f){a2.x, a2.y}; vsum[jb][1] += (v2f){a2.z, a2.w};
                vsum[jb][2] += (v2f){c2.x, c2.y}; vsum[jb][3] += (v2f){c2.z, c2.w};
            }
        }
    }

    v2f sacc[NJB][4];
    #pragma unroll
    for (int jb = 0; jb < NJB; jb++)
        #pragma unroll
        for (int k = 0; k < 4; k++) sacc[jb][k] = (v2f){0.f, 0.f};

    // Prologue: stage W[i0] into buffer 0 (1024 float4 chunks, 4/thread).
    {
        const float* wg = w + (size_t)i0 * WTILE;
        #pragma unroll
        for (int j = 0; j < 4; j++) {
            const int c = tid + j * 256;
            float4 v4 = *(const float4*)(wg + c * 4);
            *(float4*)&Wsh[0][(c >> 5) * WS + (c & 31) * 4] = v4;
        }
    }
    __syncthreads();

    for (int ii = 0; ii < IC; ii++) {
        const float* wcur = Wsh[ii & 1];
        const bool pf = (ii + 1 < IC);
        float4 t0, t1, t2, t3;            // W[i+1] in flight during compute
        if (pf) {
            const float* wg = w + (size_t)(i0 + ii + 1) * WTILE;
            t0 = *(const float4*)(wg + (tid      ) * 4);
            t1 = *(const float4*)(wg + (tid + 256) * 4);
            t2 = *(const float4*)(wg + (tid + 512) * 4);
            t3 = *(const float4*)(wg + (tid + 768) * 4);
        }

        // u via broadcast global loads (wave-uniform address)
        float us[NJB][8];
        #pragma unroll
        for (int jb = 0; jb < NJB; jb++) {
            const float* ub = u + ((size_t)(bbase + bq * NJB + jb) * II + (i0 + ii)) * DD;
            float4 a = *(const float4*)ub;
            float4 c = *(const float4*)(ub + 4);
            us[jb][0] = a.x; us[jb][1] = a.y; us[jb][2] = a.z; us[jb][3] = a.w;
            us[jb][4] = c.x; us[jb][5] = c.y; us[jb][6] = c.z; us[jb][7] = c.w;
        }

        // u_hat[b, i, o, h-half] = sum_d u[b,i,d] * W[i,o,d,h]  (packed pairs)
        v2f uh[NJB][4];
        #pragma unroll
        for (int jb = 0; jb < NJB; jb++)
            #pragma unroll
            for (int k = 0; k < 4; k++) uh[jb][k] = (v2f){0.f, 0.f};
        #pragma unroll
        for (int d = 0; d < DD; d++) {
            const float* wp = &wcur[o * WS + d * HH + hofs];
            float4 wa = *(const float4*)wp;
            float4 wc = *(const float4*)(wp + 4);
            v2f wv[4] = { (v2f){wa.x, wa.y}, (v2f){wa.z, wa.w},
                          (v2f){wc.x, wc.y}, (v2f){wc.z, wc.w} };
            #pragma unroll
            for (int jb = 0; jb < NJB; jb++) {
                const v2f usd = (v2f){us[jb][d], us[jb][d]};
                #pragma unroll
                for (int k = 0; k < 4; k++)
                    uh[jb][k] = __builtin_elementwise_fma(usd, wv[k], uh[jb][k]);
            }
        }

        // coupling: softmax over o of (vsum . u_hat); PASS 0 -> uniform 1/32
        float cc[NJB];
        if (PASS == 0) {
            #pragma unroll
            for (int jb = 0; jb < NJB; jb++) cc[jb] = 1.0f / 32.0f;
        } else {
            #pragma unroll
            for (int jb = 0; jb < NJB; jb++) {
                v2f lg2 = (v2f){0.f, 0.f};
                #pragma unroll
                for (int k = 0; k < 4; k++)
                    lg2 = __builtin_elementwise_fma(vsum[jb][k], uh[jb][k], lg2);
                float lg = lg2.x + lg2.y;
                lg += __shfl_xor(lg, 32, 64);      // combine h-halves
                const float e = __expf(lg);        // |lg| small -> no max-sub
                const float se = o_sum32(e);       // 4 DPP adds + 1 swizzle
                cc[jb] = __fdividef(e, se);
            }
        }

        #pragma unroll
        for (int jb = 0; jb < NJB; jb++) {
            const v2f ccs = (v2f){cc[jb], cc[jb]};
            #pragma unroll
            for (int k = 0; k < 4; k++)
                sacc[jb][k] = __builtin_elementwise_fma(ccs, uh[jb][k], sacc[jb][k]);
        }

        // write W[i+1] into the other buffer (vmcnt wait lands here, post-compute)
        if (pf) {
            float* wn = Wsh[(ii + 1) & 1];
            const int c0 = tid, c1 = tid + 256, c2 = tid + 512, c3 = tid + 768;
            *(float4*)&wn[(c0 >> 5) * WS + (c0 & 31) * 4] = t0;
            *(float4*)&wn[(c1 >> 5) * WS + (c1 & 31) * 4] = t1;
            *(float4*)&wn[(c2 >> 5) * WS + (c2 & 31) * 4] = t2;
            *(float4*)&wn[(c3 >> 5) * WS + (c3 & 31) * 4] = t3;
        }
        __syncthreads();
    }

    // emit partial s
    #pragma unroll
    for (int jb = 0; jb < NJB; jb++) {
        const int b = bbase + bq * NJB + jb;
        if (ATOMIC) {
            float* p = out + ((b * OO + o) * HH + hofs);
            atomicAdd(p + 0, sacc[jb][0].x); atomicAdd(p + 1, sacc[jb][0].y);
            atomicAdd(p + 2, sacc[jb][1].x); atomicAdd(p + 3, sacc[jb][1].y);
            atomicAdd(p + 4, sacc[jb][2].x); atomicAdd(p + 5, sacc[jb][2].y);
            atomicAdd(p + 6, sacc[jb][3].x); atomicAdd(p + 7, sacc[jb][3].y);
        } else {
            // per-chunk slab: fully-covered contiguous lines
            float* p = out + ((size_t)blockIdx.x * BB + b) * (OO * HH) + o * HH + hofs;
            *(float4*)p       = make_float4(sacc[jb][0].x, sacc[jb][0].y, sacc[jb][1].x, sacc[jb][1].y);
            *(float4*)(p + 4) = make_float4(sacc[jb][2].x, sacc[jb][2].y, sacc[jb][3].x, sacc[jb][3].y);
        }
    }
}

// Fused reduce-over-chunks + squash. BOH threads; t -> (b,o,h), h = t & 15.
// h-group of 16 = one DPP row -> row_sum16 replaces the shfl butterfly.
__global__ __launch_bounds__(256)
void reduce_squash_kernel(const float* __restrict__ part, float* __restrict__ v)
{
    const int t = blockIdx.x * blockDim.x + threadIdx.x;   // 0..BOH-1
    float acc = 0.f;
    #pragma unroll 16
    for (int ic = 0; ic < NIC; ic++)
        acc += part[(size_t)ic * BOH + t];
    const float sq = row_sum16(acc * acc);                 // sum over h-group (DPP row)
    const float scale = (sq / (1.f + sq)) * rsqrtf(sq + 1e-8f);
    v[t] = acc * scale;
}

// Standalone squash for the atomic tiny-ws fallback.
__global__ __launch_bounds__(256)
void squash_kernel(const float* __restrict__ s, float* __restrict__ v)
{
    const int t = blockIdx.x * blockDim.x + threadIdx.x;
    if (t >= BB * OO) return;
    const float4* sp = (const float4*)(s + t * HH);
    float4 a = sp[0], b = sp[1], c = sp[2], d = sp[3];
    float sq = a.x*a.x + a.y*a.y + a.z*a.z + a.w*a.w
             + b.x*b.x + b.y*b.y + b.z*b.z + b.w*b.w
             + c.x*c.x + c.y*c.y + c.z*c.z + c.w*c.w
             + d.x*d.x + d.y*d.y + d.z*d.z + d.w*d.w;
    const float scale = (sq / (1.f + sq)) * rsqrtf(sq + 1e-8f);
    a.x *= scale; a.y *= scale; a.z *= scale; a.w *= scale;
    b.x *= scale; b.y *= scale; b.z *= scale; b.w *= scale;
    c.x *= scale; c.y *= scale; c.z *= scale; c.w *= scale;
    d.x *= scale; d.y *= scale; d.z *= scale; d.w *= scale;
    float4* vp = (float4*)(v + t * HH);
    vp[0] = a; vp[1] = b; vp[2] = c; vp[3] = d;
}

extern "C" void kernel_launch(void* const* d_in, const int* in_sizes, int n_in,
                              void* d_out, int out_size, void* d_ws, size_t ws_size,
                              hipStream_t stream)
{
    (void)in_sizes; (void)n_in; (void)out_size;
    const float* u = (const float*)d_in[0];
    const float* w = (const float*)d_in[1];
    float* out = (float*)d_out;

    const size_t need = ((size_t)NIC * BOH + 2 * BOH) * sizeof(float);  // ~16.3 MB
    const dim3 grid(NIC, NBG), blk(256);

    if (ws_size >= need) {
        // 6 dispatches; kernel boundaries are the (cheap) grid barrier.
        // Cooperative grid.sync measured ~80-100 us/sync (R4) — do not use.
        float* part = (float*)d_ws;                 // NIC x BOH partial s
        float* v0   = part + (size_t)NIC * BOH;
        float* v1   = v0 + BOH;
        const int rblocks = BOH / 256;              // 128

        pass_kernel<0, false><<<grid, blk, 0, stream>>>(u, w, nullptr, nullptr, part);
        reduce_squash_kernel<<<rblocks, 256, 0, stream>>>(part, v0);
        pass_kernel<1, false><<<grid, blk, 0, stream>>>(u, w, v0, nullptr, part);
        reduce_squash_kernel<<<rblocks, 256, 0, stream>>>(part, v1);
        pass_kernel<2, false><<<grid, blk, 0, stream>>>(u, w, v0, v1, part);
        reduce_squash_kernel<<<rblocks, 256, 0, stream>>>(part, out);
    } else {
        // Tiny-ws fallback: atomic path.
        float* s0 = (float*)d_ws;
        float* s1 = s0 + BOH;
        float* v0 = s1 + BOH;
        float* v1 = v0 + BOH;
        hipMemsetAsync(d_ws, 0, 2 * BOH * sizeof(float), stream);
        hipMemsetAsync(d_out, 0, BOH * sizeof(float), stream);
        const int sq_blocks = (BB * OO + 255) / 256;

        pass_kernel<0, true><<<grid, blk, 0, stream>>>(u, w, nullptr, nullptr, s0);
        squash_kernel<<<sq_blocks, 256, 0, stream>>>(s0, v0);
        pass_kernel<1, true><<<grid, blk, 0, stream>>>(u, w, v0, nullptr, s1);
        squash_kernel<<<sq_blocks, 256, 0, stream>>>(s1, v1);
        pass_kernel<2, true><<<grid, blk, 0, stream>>>(u, w, v0, v1, out);
        squash_kernel<<<sq_blocks, 256, 0, stream>>>(out, out);
    }
}